// Round 1
// baseline (488.717 us; speedup 1.0000x reference)
//
#include <hip/hip_runtime.h>
#include <hip/hip_bf16.h>

typedef __attribute__((ext_vector_type(8))) short short8;
typedef __attribute__((ext_vector_type(4))) float f32x4;

#define CC 0.01f
#define SCRT 0.1f  // sqrt(c)

static __device__ __forceinline__ unsigned short f2bf(float f) {
  union { float f; unsigned int u; } cv; cv.f = f;
  unsigned int u = cv.u;
  unsigned int r = (u + 0x7fffu + ((u >> 16) & 1u)) >> 16;  // RNE
  return (unsigned short)r;
}
static __device__ __forceinline__ float bf2f(unsigned short u) {
  union { unsigned int u; float f; } cv; cv.u = ((unsigned int)u) << 16;
  return cv.f;
}

#define GLOAD16(g, l) __builtin_amdgcn_global_load_lds( \
    (const __attribute__((address_space(1))) void*)(g), \
    (__attribute__((address_space(3))) void*)(l), 16, 0, 0)

// ---------------------------------------------------------------------------
// Kernel 1: gather entity rows for s,o; apply log-map scale; write bf16.
// One block (256 thr) per triplet. sto[i][0:1024]=s_tan, [1024:2048]=o_tan.
__global__ void k_prep_sto(const float* __restrict__ ent,
                           const int* __restrict__ trip,
                           unsigned short* __restrict__ sto) {
  int i = blockIdx.x;
  int t = threadIdx.x;
  size_t si = (size_t)trip[i * 3 + 0];
  size_t oi = (size_t)trip[i * 3 + 2];
  float4 vs = ((const float4*)(ent + si * 1024))[t];
  float4 vo = ((const float4*)(ent + oi * 1024))[t];
  float ss = vs.x * vs.x + vs.y * vs.y + vs.z * vs.z + vs.w * vs.w;
  float so = vo.x * vo.x + vo.y * vo.y + vo.z * vo.z + vo.w * vo.w;
#pragma unroll
  for (int off = 32; off > 0; off >>= 1) {
    ss += __shfl_down(ss, off, 64);
    so += __shfl_down(so, off, 64);
  }
  __shared__ float red[8];
  if ((t & 63) == 0) { red[t >> 6] = ss; red[4 + (t >> 6)] = so; }
  __syncthreads();
  float tot_s = red[0] + red[1] + red[2] + red[3];
  float tot_o = red[4] + red[5] + red[6] + red[7];

  float ns = fmaxf(sqrtf(tot_s), 1e-10f);
  float scn_s = SCRT * ns;
  float fs = atanhf(fminf(scn_s, 1.0f - 1e-7f)) / scn_s;

  float no = fmaxf(sqrtf(tot_o), 1e-10f);
  float scn_o = SCRT * no;
  float fo = atanhf(fminf(scn_o, 1.0f - 1e-7f)) / scn_o;

  ushort4 os, oo;
  os.x = f2bf(vs.x * fs); os.y = f2bf(vs.y * fs);
  os.z = f2bf(vs.z * fs); os.w = f2bf(vs.w * fs);
  oo.x = f2bf(vo.x * fo); oo.y = f2bf(vo.y * fo);
  oo.z = f2bf(vo.z * fo); oo.w = f2bf(vo.w * fo);
  ((ushort4*)(sto + (size_t)i * 2048))[t] = os;
  ((ushort4*)(sto + (size_t)i * 2048 + 1024))[t] = oo;
}

// ---------------------------------------------------------------------------
// Kernel 2: build wt[n][k] = (k<1024 ? W_s[k][n] : W_o[k-1024][n]) as bf16.
__global__ void k_wt(const float* __restrict__ Ws, const float* __restrict__ Wo,
                     unsigned short* __restrict__ wtb) {
  int idx = blockIdx.x * 256 + threadIdx.x;   // 1024*2048 total
  int n = idx >> 11;
  int k = idx & 2047;
  float v = (k < 1024) ? Ws[k * 1024 + n] : Wo[(k - 1024) * 1024 + n];
  wtb[idx] = f2bf(v);
}

// ---------------------------------------------------------------------------
// Kernel 3: rel prep: relb = bf16(rel_embedding); yy = f^2*sumsq; fj = f.
__global__ void k_rel(const float* __restrict__ rel,
                      unsigned short* __restrict__ relb,
                      float* __restrict__ yy, float* __restrict__ fj) {
  int j = blockIdx.x;
  int t = threadIdx.x;
  float4 v = ((const float4*)(rel + (size_t)j * 1024))[t];
  float ss = v.x * v.x + v.y * v.y + v.z * v.z + v.w * v.w;
#pragma unroll
  for (int off = 32; off > 0; off >>= 1) ss += __shfl_down(ss, off, 64);
  __shared__ float red[4];
  if ((t & 63) == 0) red[t >> 6] = ss;
  __syncthreads();
  ushort4 o;
  o.x = f2bf(v.x); o.y = f2bf(v.y); o.z = f2bf(v.z); o.w = f2bf(v.w);
  ((ushort4*)(relb + (size_t)j * 1024))[t] = o;
  if (t == 0) {
    float tot = red[0] + red[1] + red[2] + red[3];
    float n = fmaxf(sqrtf(tot), 1e-10f);
    float scn = SCRT * n;
    float f = tanhf(scn) / scn;
    yy[j] = f * f * tot;
    fj[j] = f;
  }
}

// ---------------------------------------------------------------------------
// Kernel 5: query stats from qt bf16: xx = f^2*sumsq; fi = f.
__global__ void k_qstat(const unsigned short* __restrict__ qt,
                        float* __restrict__ xx, float* __restrict__ fi) {
  int i = blockIdx.x;
  int t = threadIdx.x;
  ushort4 v = ((const ushort4*)(qt + (size_t)i * 1024))[t];
  float a = bf2f(v.x), b = bf2f(v.y), c = bf2f(v.z), d = bf2f(v.w);
  float ss = a * a + b * b + c * c + d * d;
#pragma unroll
  for (int off = 32; off > 0; off >>= 1) ss += __shfl_down(ss, off, 64);
  __shared__ float red[4];
  if ((t & 63) == 0) red[t >> 6] = ss;
  __syncthreads();
  if (t == 0) {
    float tot = red[0] + red[1] + red[2] + red[3];
    float n = fmaxf(sqrtf(tot), 1e-10f);
    float scn = SCRT * n;
    float f = tanhf(scn) / scn;
    xx[i] = f * f * tot;
    fi[i] = f;
  }
}

// ---------------------------------------------------------------------------
// GEMM1: qt[M][1024] = sto[M][2048] @ wt^T  (wt is [1024][2048], BT layout)
// 128x128 tile, BK=32, 4 waves (2x2), 16x16x32 bf16 MFMA, global_load_lds.
__global__ void k_gemm1(const unsigned short* __restrict__ A,
                        const unsigned short* __restrict__ BT,
                        unsigned short* __restrict__ Cq) {
  const int K = 2048;
  __shared__ unsigned short As[128 * 32];
  __shared__ unsigned short Bs[128 * 32];
  int t = threadIdx.x;
  int lane = t & 63;
  int w = t >> 6;
  int wr = w >> 1, wc = w & 1;
  size_t gm0 = (size_t)blockIdx.y * 128;
  int gn0 = blockIdx.x * 128;

  f32x4 acc[4][4] = {};

  int r1 = t >> 2;
  int r2 = r1 + 64;
  int cp = t & 3;
  int ch1 = cp ^ ((r1 >> 1) & 3);
  int ch2 = cp ^ ((r2 >> 1) & 3);
  const unsigned short* a1 = A + (gm0 + r1) * K + ch1 * 8;
  const unsigned short* a2 = A + (gm0 + r2) * K + ch2 * 8;
  const unsigned short* b1 = BT + (size_t)(gn0 + r1) * K + ch1 * 8;
  const unsigned short* b2 = BT + (size_t)(gn0 + r2) * K + ch2 * 8;
  char* as_base = (char*)As + w * 1024;
  char* bs_base = (char*)Bs + w * 1024;

  for (int kt = 0; kt < K / 32; ++kt) {
    int ko = kt * 32;
    GLOAD16(a1 + ko, as_base);
    GLOAD16(a2 + ko, as_base + 4096);
    GLOAD16(b1 + ko, bs_base);
    GLOAD16(b2 + ko, bs_base + 4096);
    asm volatile("s_waitcnt vmcnt(0)");
    __syncthreads();
    short8 af[4], bfr[4];
#pragma unroll
    for (int m = 0; m < 4; ++m) {
      int row = wr * 64 + m * 16 + (lane & 15);
      int c2 = (lane >> 4) ^ ((row >> 1) & 3);
      af[m] = *(const short8*)((const char*)As + row * 64 + c2 * 16);
      int rowb = wc * 64 + m * 16 + (lane & 15);
      int c2b = (lane >> 4) ^ ((rowb >> 1) & 3);
      bfr[m] = *(const short8*)((const char*)Bs + rowb * 64 + c2b * 16);
    }
#pragma unroll
    for (int m = 0; m < 4; ++m)
#pragma unroll
      for (int n = 0; n < 4; ++n)
        acc[m][n] = __builtin_amdgcn_mfma_f32_16x16x32_bf16(af[m], bfr[n], acc[m][n], 0, 0, 0);
    __syncthreads();
  }
#pragma unroll
  for (int m = 0; m < 4; ++m)
#pragma unroll
    for (int n = 0; n < 4; ++n) {
      int col = gn0 + wc * 64 + n * 16 + (lane & 15);
      size_t row0 = gm0 + wr * 64 + m * 16 + (lane >> 4) * 4;
#pragma unroll
      for (int j = 0; j < 4; ++j)
        Cq[(row0 + j) * 1024 + col] = f2bf(acc[m][n][j]);
    }
}

// ---------------------------------------------------------------------------
// GEMM2 + epilogue: out[i][j] = -dist_sq + bias[j]
__global__ void k_gemm2(const unsigned short* __restrict__ A,
                        const unsigned short* __restrict__ BT,
                        const float* __restrict__ xx, const float* __restrict__ fi,
                        const float* __restrict__ yy, const float* __restrict__ fj,
                        const float* __restrict__ bias,
                        float* __restrict__ out) {
  const int K = 1024;
  const int N = 2000;
  __shared__ unsigned short As[128 * 32];
  __shared__ unsigned short Bs[128 * 32];
  int t = threadIdx.x;
  int lane = t & 63;
  int w = t >> 6;
  int wr = w >> 1, wc = w & 1;
  size_t gm0 = (size_t)blockIdx.y * 128;
  int gn0 = blockIdx.x * 128;

  f32x4 acc[4][4] = {};

  int r1 = t >> 2;
  int r2 = r1 + 64;
  int cp = t & 3;
  int ch1 = cp ^ ((r1 >> 1) & 3);
  int ch2 = cp ^ ((r2 >> 1) & 3);
  int gb1 = min(gn0 + r1, N - 1);
  int gb2 = min(gn0 + r2, N - 1);
  const unsigned short* a1 = A + (gm0 + r1) * K + ch1 * 8;
  const unsigned short* a2 = A + (gm0 + r2) * K + ch2 * 8;
  const unsigned short* b1 = BT + (size_t)gb1 * K + ch1 * 8;
  const unsigned short* b2 = BT + (size_t)gb2 * K + ch2 * 8;
  char* as_base = (char*)As + w * 1024;
  char* bs_base = (char*)Bs + w * 1024;

  for (int kt = 0; kt < K / 32; ++kt) {
    int ko = kt * 32;
    GLOAD16(a1 + ko, as_base);
    GLOAD16(a2 + ko, as_base + 4096);
    GLOAD16(b1 + ko, bs_base);
    GLOAD16(b2 + ko, bs_base + 4096);
    asm volatile("s_waitcnt vmcnt(0)");
    __syncthreads();
    short8 af[4], bfr[4];
#pragma unroll
    for (int m = 0; m < 4; ++m) {
      int row = wr * 64 + m * 16 + (lane & 15);
      int c2 = (lane >> 4) ^ ((row >> 1) & 3);
      af[m] = *(const short8*)((const char*)As + row * 64 + c2 * 16);
      int rowb = wc * 64 + m * 16 + (lane & 15);
      int c2b = (lane >> 4) ^ ((rowb >> 1) & 3);
      bfr[m] = *(const short8*)((const char*)Bs + rowb * 64 + c2b * 16);
    }
#pragma unroll
    for (int m = 0; m < 4; ++m)
#pragma unroll
      for (int n = 0; n < 4; ++n)
        acc[m][n] = __builtin_amdgcn_mfma_f32_16x16x32_bf16(af[m], bfr[n], acc[m][n], 0, 0, 0);
    __syncthreads();
  }

#pragma unroll
  for (int m = 0; m < 4; ++m)
#pragma unroll
    for (int n = 0; n < 4; ++n) {
      int col = gn0 + wc * 64 + n * 16 + (lane & 15);
      if (col < N) {
        float yj = yy[col];
        float fjc = fj[col];
        float bj = bias[col];
        size_t row0 = gm0 + wr * 64 + m * 16 + (lane >> 4) * 4;
#pragma unroll
        for (int j = 0; j < 4; ++j) {
          size_t row = row0 + j;
          float G = acc[m][n][j];
          float xi = xx[row];
          float fic = fi[row];
          float xyv = -(fic * fjc) * G;
          float Aa = 1.0f + 2.0f * CC * xyv + CC * yj;
          float Bb = 1.0f - CC * xi;
          float num = Aa * Aa * xi + 2.0f * Aa * Bb * xyv + Bb * Bb * yj;
          float den = 1.0f + 2.0f * CC * xyv + CC * CC * xi * yj;
          out[row * (size_t)N + col] = -(num / (den * den)) + bj;
        }
      }
    }
}

// ---------------------------------------------------------------------------
extern "C" void kernel_launch(void* const* d_in, const int* in_sizes, int n_in,
                              void* d_out, int out_size, void* d_ws, size_t ws_size,
                              hipStream_t stream) {
  const float* ent = (const float*)d_in[0];
  const float* rel = (const float*)d_in[1];
  const int* trip = (const int*)d_in[2];
  const float* Ws = (const float*)d_in[3];
  const float* Wo = (const float*)d_in[4];
  const float* bias = (const float*)d_in[5];
  float* out = (float*)d_out;

  char* ws = (char*)d_ws;
  unsigned short* sto = (unsigned short*)(ws);                    // 32768*2048*2 = 134217728
  unsigned short* wt  = (unsigned short*)(ws + 134217728);        // 1024*2048*2  =   4194304
  unsigned short* qt  = (unsigned short*)(ws + 138412032);        // 32768*1024*2 =  67108864
  unsigned short* relb= (unsigned short*)(ws + 205520896);        // 2000*1024*2  =   4096000
  float* xx = (float*)(ws + 209616896);                           // 131072
  float* fi = (float*)(ws + 209747968);                           // 131072
  float* yy = (float*)(ws + 209879040);                           // 8192
  float* fj = (float*)(ws + 209887232);                           // 8192

  k_prep_sto<<<dim3(32768), dim3(256), 0, stream>>>(ent, trip, sto);
  k_wt<<<dim3((1024 * 2048) / 256), dim3(256), 0, stream>>>(Ws, Wo, wt);
  k_rel<<<dim3(2000), dim3(256), 0, stream>>>(rel, relb, yy, fj);
  k_gemm1<<<dim3(8, 256), dim3(256), 0, stream>>>(sto, wt, qt);
  k_qstat<<<dim3(32768), dim3(256), 0, stream>>>(qt, xx, fi);
  k_gemm2<<<dim3(16, 256), dim3(256), 0, stream>>>(qt, relb, xx, fi, yy, fj, bias, out);
}

// Round 2
// 466.170 us; speedup vs baseline: 1.0484x; 1.0484x over previous
//
#include <hip/hip_runtime.h>
#include <hip/hip_bf16.h>

typedef __attribute__((ext_vector_type(8))) short short8;
typedef __attribute__((ext_vector_type(4))) float f32x4;

#define CC 0.01f
#define SCRT 0.1f  // sqrt(c)

static __device__ __forceinline__ unsigned short f2bf(float f) {
  union { float f; unsigned int u; } cv; cv.f = f;
  unsigned int u = cv.u;
  unsigned int r = (u + 0x7fffu + ((u >> 16) & 1u)) >> 16;  // RNE
  return (unsigned short)r;
}
static __device__ __forceinline__ float bf2f(unsigned short u) {
  union { unsigned int u; float f; } cv; cv.u = ((unsigned int)u) << 16;
  return cv.f;
}

#define GLOAD16(g, l) __builtin_amdgcn_global_load_lds( \
    (const __attribute__((address_space(1))) void*)(g), \
    (__attribute__((address_space(3))) void*)(l), 16, 0, 0)

// ---------------------------------------------------------------------------
// Kernel 1: gather entity rows for s,o; apply log-map scale; write bf16.
__global__ void k_prep_sto(const float* __restrict__ ent,
                           const int* __restrict__ trip,
                           unsigned short* __restrict__ sto) {
  int i = blockIdx.x;
  int t = threadIdx.x;
  size_t si = (size_t)trip[i * 3 + 0];
  size_t oi = (size_t)trip[i * 3 + 2];
  float4 vs = ((const float4*)(ent + si * 1024))[t];
  float4 vo = ((const float4*)(ent + oi * 1024))[t];
  float ss = vs.x * vs.x + vs.y * vs.y + vs.z * vs.z + vs.w * vs.w;
  float so = vo.x * vo.x + vo.y * vo.y + vo.z * vo.z + vo.w * vo.w;
#pragma unroll
  for (int off = 32; off > 0; off >>= 1) {
    ss += __shfl_down(ss, off, 64);
    so += __shfl_down(so, off, 64);
  }
  __shared__ float red[8];
  if ((t & 63) == 0) { red[t >> 6] = ss; red[4 + (t >> 6)] = so; }
  __syncthreads();
  float tot_s = red[0] + red[1] + red[2] + red[3];
  float tot_o = red[4] + red[5] + red[6] + red[7];

  float ns = fmaxf(sqrtf(tot_s), 1e-10f);
  float scn_s = SCRT * ns;
  float fs = atanhf(fminf(scn_s, 1.0f - 1e-7f)) / scn_s;

  float no = fmaxf(sqrtf(tot_o), 1e-10f);
  float scn_o = SCRT * no;
  float fo = atanhf(fminf(scn_o, 1.0f - 1e-7f)) / scn_o;

  ushort4 os, oo;
  os.x = f2bf(vs.x * fs); os.y = f2bf(vs.y * fs);
  os.z = f2bf(vs.z * fs); os.w = f2bf(vs.w * fs);
  oo.x = f2bf(vo.x * fo); oo.y = f2bf(vo.y * fo);
  oo.z = f2bf(vo.z * fo); oo.w = f2bf(vo.w * fo);
  ((ushort4*)(sto + (size_t)i * 2048))[t] = os;
  ((ushort4*)(sto + (size_t)i * 2048 + 1024))[t] = oo;
}

// ---------------------------------------------------------------------------
// Kernel 2: build wt[n][k] = (k<1024 ? W_s[k][n] : W_o[k-1024][n]) as bf16.
__global__ void k_wt(const float* __restrict__ Ws, const float* __restrict__ Wo,
                     unsigned short* __restrict__ wtb) {
  int idx = blockIdx.x * 256 + threadIdx.x;   // 1024*2048 total
  int n = idx >> 11;
  int k = idx & 2047;
  float v = (k < 1024) ? Ws[k * 1024 + n] : Wo[(k - 1024) * 1024 + n];
  wtb[idx] = f2bf(v);
}

// ---------------------------------------------------------------------------
// Kernel 3: rel prep: relb = bf16(rel_embedding); yy = f^2*sumsq; fj = f.
__global__ void k_rel(const float* __restrict__ rel,
                      unsigned short* __restrict__ relb,
                      float* __restrict__ yy, float* __restrict__ fj) {
  int j = blockIdx.x;
  int t = threadIdx.x;
  float4 v = ((const float4*)(rel + (size_t)j * 1024))[t];
  float ss = v.x * v.x + v.y * v.y + v.z * v.z + v.w * v.w;
#pragma unroll
  for (int off = 32; off > 0; off >>= 1) ss += __shfl_down(ss, off, 64);
  __shared__ float red[4];
  if ((t & 63) == 0) red[t >> 6] = ss;
  __syncthreads();
  ushort4 o;
  o.x = f2bf(v.x); o.y = f2bf(v.y); o.z = f2bf(v.z); o.w = f2bf(v.w);
  ((ushort4*)(relb + (size_t)j * 1024))[t] = o;
  if (t == 0) {
    float tot = red[0] + red[1] + red[2] + red[3];
    float n = fmaxf(sqrtf(tot), 1e-10f);
    float scn = SCRT * n;
    float f = tanhf(scn) / scn;
    yy[j] = f * f * tot;
    fj[j] = f;
  }
}

// ---------------------------------------------------------------------------
// Kernel 5: query stats from qt bf16: xx = f^2*sumsq; fi = f.
__global__ void k_qstat(const unsigned short* __restrict__ qt,
                        float* __restrict__ xx, float* __restrict__ fi) {
  int i = blockIdx.x;
  int t = threadIdx.x;
  ushort4 v = ((const ushort4*)(qt + (size_t)i * 1024))[t];
  float a = bf2f(v.x), b = bf2f(v.y), c = bf2f(v.z), d = bf2f(v.w);
  float ss = a * a + b * b + c * c + d * d;
#pragma unroll
  for (int off = 32; off > 0; off >>= 1) ss += __shfl_down(ss, off, 64);
  __shared__ float red[4];
  if ((t & 63) == 0) red[t >> 6] = ss;
  __syncthreads();
  if (t == 0) {
    float tot = red[0] + red[1] + red[2] + red[3];
    float n = fmaxf(sqrtf(tot), 1e-10f);
    float scn = SCRT * n;
    float f = tanhf(scn) / scn;
    xx[i] = f * f * tot;
    fi[i] = f;
  }
}

// ---------------------------------------------------------------------------
// 256x256-tile GEMM, 8 waves (2M x 4N), BK=32, 4-deep LDS slot pipeline with
// counted vmcnt (never 0 in steady state), raw s_barrier, setprio around MFMA.
// A[M][K] bf16, BT[NB][K] bf16 (B transposed). G2: fused Mobius epilogue.
template<int K, bool G2>
__global__ __launch_bounds__(512, 2) void k_gemm256(
    const unsigned short* __restrict__ A,
    const unsigned short* __restrict__ BT,
    unsigned short* __restrict__ Cq,
    const float* __restrict__ xx, const float* __restrict__ fi,
    const float* __restrict__ yy, const float* __restrict__ fj,
    const float* __restrict__ bias, float* __restrict__ out,
    int nxb) {
  constexpr int NT = K / 32;
  // 4 slots x (256 rows x 32 cols bf16) = 4 x 16 KB each for A and B = 128 KB
  __shared__ __align__(16) unsigned short AS[4 * 8192];
  __shared__ __align__(16) unsigned short BS[4 * 8192];

  // XCD-aware swizzle (grid divisible by 8)
  int nwg = gridDim.x;
  int bid = blockIdx.x;
  int wg = (bid & 7) * (nwg >> 3) + (bid >> 3);
  int bx = wg % nxb;
  int by = wg / nxb;
  size_t gm0 = (size_t)by * 256;
  int gn0 = bx * 256;

  int t = threadIdx.x;
  int lane = t & 63;
  int w = t >> 6;        // 0..7
  int wm = w >> 2;       // 0..1 -> 128-row block
  int wn = w & 3;        // 0..3 -> 64-col block
  int fr = lane & 15;
  int k0 = lane >> 4;

  // staging source (pre-swizzled global column so LDS ends up XOR-swizzled)
  int srow = t >> 2;                       // 0..127
  int ch = (t & 3) ^ ((srow >> 1) & 3);
  const unsigned short* pa0 = A + (gm0 + srow) * (size_t)K + ch * 8;
  const unsigned short* pa1 = pa0 + (size_t)128 * K;
  int br0 = gn0 + srow, br1 = gn0 + 128 + srow;
  if (G2) { br0 = min(br0, 1999); br1 = min(br1, 1999); }
  const unsigned short* pb0 = BT + (size_t)br0 * K + ch * 8;
  const unsigned short* pb1 = BT + (size_t)br1 * K + ch * 8;

  char* aw = (char*)AS + w * 1024;         // wave-uniform LDS stage base
  char* bw = (char*)BS + w * 1024;

  // fragment read base: column swizzle constant across m (128/64 offsets are
  // multiples of 8 rows, so (row>>1)&3 depends only on fr)
  unsigned fca = (unsigned)((k0 ^ ((fr >> 1) & 3)) << 4);
  const char* ard = (const char*)AS + (wm * 128 + fr) * 64 + fca;
  const char* brd = (const char*)BS + (wn * 64 + fr) * 64 + fca;

  f32x4 acc[8][4] = {};

  // prologue: stage tiles 0,1,2 into slots 0,1,2 (12 loads/thread)
#pragma unroll
  for (int p = 0; p < 3; ++p) {
    int ko = p * 32;
    GLOAD16(pa0 + ko, aw + p * 16384);
    GLOAD16(pa1 + ko, aw + p * 16384 + 8192);
    GLOAD16(pb0 + ko, bw + p * 16384);
    GLOAD16(pb1 + ko, bw + p * 16384 + 8192);
  }
  asm volatile("s_waitcnt vmcnt(8)" ::: "memory");  // tile 0 landed
  __builtin_amdgcn_s_barrier();
  asm volatile("" ::: "memory");

  for (int kt = 0; kt < NT; ++kt) {
    int cur = kt & 3;
    int stg = (kt + 3) & 3;
    const char* ac = ard + cur * 16384;
    const char* bc = brd + cur * 16384;
    bool do_stage = (kt + 3 < NT);
    int ko = (kt + 3) * 32;

    // ---- phase 0: stage next A tile; compute m0-3 x n0-3
    if (do_stage) {
      GLOAD16(pa0 + ko, aw + stg * 16384);
      GLOAD16(pa1 + ko, aw + stg * 16384 + 8192);
    }
    short8 af[4], bv[4];
#pragma unroll
    for (int m = 0; m < 4; ++m) af[m] = *(const short8*)(ac + m * 1024);
#pragma unroll
    for (int n = 0; n < 4; ++n) bv[n] = *(const short8*)(bc + n * 1024);
    __builtin_amdgcn_s_setprio(1);
#pragma unroll
    for (int m = 0; m < 4; ++m)
#pragma unroll
      for (int n = 0; n < 4; ++n)
        acc[m][n] = __builtin_amdgcn_mfma_f32_16x16x32_bf16(af[m], bv[n], acc[m][n], 0, 0, 0);
    __builtin_amdgcn_s_setprio(0);

    // ---- phase 1: stage next B tile; compute m4-7 x n0-3
    if (do_stage) {
      GLOAD16(pb0 + ko, bw + stg * 16384);
      GLOAD16(pb1 + ko, bw + stg * 16384 + 8192);
    }
#pragma unroll
    for (int m = 0; m < 4; ++m) af[m] = *(const short8*)(ac + 4096 + m * 1024);
    __builtin_amdgcn_s_setprio(1);
#pragma unroll
    for (int m = 0; m < 4; ++m)
#pragma unroll
      for (int n = 0; n < 4; ++n)
        acc[4 + m][n] = __builtin_amdgcn_mfma_f32_16x16x32_bf16(af[m], bv[n], acc[4 + m][n], 0, 0, 0);
    __builtin_amdgcn_s_setprio(0);

    // ---- boundary: drain exactly tile kt+1 (3 tiles x 4 loads in flight)
    if (kt < NT - 3) {
      asm volatile("s_waitcnt vmcnt(8)" ::: "memory");
    } else if (kt == NT - 3) {
      asm volatile("s_waitcnt vmcnt(4)" ::: "memory");
    } else if (kt == NT - 2) {
      asm volatile("s_waitcnt vmcnt(0)" ::: "memory");
    }
    if (kt < NT - 1) {
      __builtin_amdgcn_s_barrier();
      asm volatile("" ::: "memory");
    }
  }

  // ---- epilogue
  if (!G2) {
#pragma unroll
    for (int m = 0; m < 8; ++m)
#pragma unroll
      for (int n = 0; n < 4; ++n) {
        int col = gn0 + wn * 64 + n * 16 + fr;
        size_t row0 = gm0 + wm * 128 + m * 16 + k0 * 4;
#pragma unroll
        for (int j = 0; j < 4; ++j)
          Cq[(row0 + j) * 1024 + col] = f2bf(acc[m][n][j]);
      }
  } else {
#pragma unroll
    for (int m = 0; m < 8; ++m)
#pragma unroll
      for (int n = 0; n < 4; ++n) {
        int col = gn0 + wn * 64 + n * 16 + fr;
        if (col < 2000) {
          float yj = yy[col], fjc = fj[col], bj = bias[col];
          size_t row0 = gm0 + wm * 128 + m * 16 + k0 * 4;
#pragma unroll
          for (int j = 0; j < 4; ++j) {
            size_t row = row0 + j;
            float G = acc[m][n][j];
            float xi = xx[row], fic = fi[row];
            float xyv = -(fic * fjc) * G;
            float Aa = 1.0f + 2.0f * CC * xyv + CC * yj;
            float Bb = 1.0f - CC * xi;
            float num = Aa * Aa * xi + 2.0f * Aa * Bb * xyv + Bb * Bb * yj;
            float den = 1.0f + 2.0f * CC * xyv + CC * CC * xi * yj;
            out[row * 2000 + col] = -(num / (den * den)) + bj;
          }
        }
      }
  }
}

// ---------------------------------------------------------------------------
extern "C" void kernel_launch(void* const* d_in, const int* in_sizes, int n_in,
                              void* d_out, int out_size, void* d_ws, size_t ws_size,
                              hipStream_t stream) {
  const float* ent = (const float*)d_in[0];
  const float* rel = (const float*)d_in[1];
  const int* trip = (const int*)d_in[2];
  const float* Ws = (const float*)d_in[3];
  const float* Wo = (const float*)d_in[4];
  const float* bias = (const float*)d_in[5];
  float* out = (float*)d_out;

  char* ws = (char*)d_ws;
  unsigned short* sto = (unsigned short*)(ws);                    // 32768*2048*2 = 134217728
  unsigned short* wt  = (unsigned short*)(ws + 134217728);        // 1024*2048*2  =   4194304
  unsigned short* qt  = (unsigned short*)(ws + 138412032);        // 32768*1024*2 =  67108864
  unsigned short* relb= (unsigned short*)(ws + 205520896);        // 2000*1024*2  =   4096000
  float* xx = (float*)(ws + 209616896);                           // 131072
  float* fi = (float*)(ws + 209747968);                           // 131072
  float* yy = (float*)(ws + 209879040);                           // 8192
  float* fj = (float*)(ws + 209887232);                           // 8192

  k_prep_sto<<<dim3(32768), dim3(256), 0, stream>>>(ent, trip, sto);
  k_wt<<<dim3((1024 * 2048) / 256), dim3(256), 0, stream>>>(Ws, Wo, wt);
  k_rel<<<dim3(2000), dim3(256), 0, stream>>>(rel, relb, yy, fj);

  // GEMM1: qt[32768][1024] = sto[32768][2048] @ wt^T ; grid 4x128 = 512
  k_gemm256<2048, false><<<dim3(512), dim3(512), 0, stream>>>(
      sto, wt, qt, xx, fi, yy, fj, bias, out, 4);

  k_qstat<<<dim3(32768), dim3(256), 0, stream>>>(qt, xx, fi);

  // GEMM2 + epilogue: grid 8x128 = 1024
  k_gemm256<1024, true><<<dim3(1024), dim3(512), 0, stream>>>(
      qt, relb, qt /*unused*/, xx, fi, yy, fj, bias, out, 8);
}

// Round 3
// 440.013 us; speedup vs baseline: 1.1107x; 1.0594x over previous
//
#include <hip/hip_runtime.h>
#include <hip/hip_bf16.h>

typedef __attribute__((ext_vector_type(8))) short short8;
typedef __attribute__((ext_vector_type(4))) float f32x4;

#define CC 0.01f
#define SCRT 0.1f  // sqrt(c)

static __device__ __forceinline__ unsigned short f2bf(float f) {
  union { float f; unsigned int u; } cv; cv.f = f;
  unsigned int u = cv.u;
  unsigned int r = (u + 0x7fffu + ((u >> 16) & 1u)) >> 16;  // RNE
  return (unsigned short)r;
}
static __device__ __forceinline__ float bf2f(unsigned short u) {
  union { unsigned int u; float f; } cv; cv.u = ((unsigned int)u) << 16;
  return cv.f;
}

#define GLOAD16(g, l) __builtin_amdgcn_global_load_lds( \
    (const __attribute__((address_space(1))) void*)(g), \
    (__attribute__((address_space(3))) void*)(l), 16, 0, 0)

// ---------------------------------------------------------------------------
// Kernel 1: gather entity rows for s,o; apply log-map scale; write bf16.
__global__ void k_prep_sto(const float* __restrict__ ent,
                           const int* __restrict__ trip,
                           unsigned short* __restrict__ sto) {
  int i = blockIdx.x;
  int t = threadIdx.x;
  size_t si = (size_t)trip[i * 3 + 0];
  size_t oi = (size_t)trip[i * 3 + 2];
  float4 vs = ((const float4*)(ent + si * 1024))[t];
  float4 vo = ((const float4*)(ent + oi * 1024))[t];
  float ss = vs.x * vs.x + vs.y * vs.y + vs.z * vs.z + vs.w * vs.w;
  float so = vo.x * vo.x + vo.y * vo.y + vo.z * vo.z + vo.w * vo.w;
#pragma unroll
  for (int off = 32; off > 0; off >>= 1) {
    ss += __shfl_down(ss, off, 64);
    so += __shfl_down(so, off, 64);
  }
  __shared__ float red[8];
  if ((t & 63) == 0) { red[t >> 6] = ss; red[4 + (t >> 6)] = so; }
  __syncthreads();
  float tot_s = red[0] + red[1] + red[2] + red[3];
  float tot_o = red[4] + red[5] + red[6] + red[7];

  float ns = fmaxf(sqrtf(tot_s), 1e-10f);
  float scn_s = SCRT * ns;
  float fs = atanhf(fminf(scn_s, 1.0f - 1e-7f)) / scn_s;

  float no = fmaxf(sqrtf(tot_o), 1e-10f);
  float scn_o = SCRT * no;
  float fo = atanhf(fminf(scn_o, 1.0f - 1e-7f)) / scn_o;

  ushort4 os, oo;
  os.x = f2bf(vs.x * fs); os.y = f2bf(vs.y * fs);
  os.z = f2bf(vs.z * fs); os.w = f2bf(vs.w * fs);
  oo.x = f2bf(vo.x * fo); oo.y = f2bf(vo.y * fo);
  oo.z = f2bf(vo.z * fo); oo.w = f2bf(vo.w * fo);
  ((ushort4*)(sto + (size_t)i * 2048))[t] = os;
  ((ushort4*)(sto + (size_t)i * 2048 + 1024))[t] = oo;
}

// ---------------------------------------------------------------------------
// Kernel 2: build wt[n][k] = (k<1024 ? W_s[k][n] : W_o[k-1024][n]) as bf16.
__global__ void k_wt(const float* __restrict__ Ws, const float* __restrict__ Wo,
                     unsigned short* __restrict__ wtb) {
  int idx = blockIdx.x * 256 + threadIdx.x;   // 1024*2048 total
  int n = idx >> 11;
  int k = idx & 2047;
  float v = (k < 1024) ? Ws[k * 1024 + n] : Wo[(k - 1024) * 1024 + n];
  wtb[idx] = f2bf(v);
}

// ---------------------------------------------------------------------------
// Kernel 3: rel prep: relb = bf16(rel_embedding); yy = f^2*sumsq; fj = f.
__global__ void k_rel(const float* __restrict__ rel,
                      unsigned short* __restrict__ relb,
                      float* __restrict__ yy, float* __restrict__ fj) {
  int j = blockIdx.x;
  int t = threadIdx.x;
  float4 v = ((const float4*)(rel + (size_t)j * 1024))[t];
  float ss = v.x * v.x + v.y * v.y + v.z * v.z + v.w * v.w;
#pragma unroll
  for (int off = 32; off > 0; off >>= 1) ss += __shfl_down(ss, off, 64);
  __shared__ float red[4];
  if ((t & 63) == 0) red[t >> 6] = ss;
  __syncthreads();
  ushort4 o;
  o.x = f2bf(v.x); o.y = f2bf(v.y); o.z = f2bf(v.z); o.w = f2bf(v.w);
  ((ushort4*)(relb + (size_t)j * 1024))[t] = o;
  if (t == 0) {
    float tot = red[0] + red[1] + red[2] + red[3];
    float n = fmaxf(sqrtf(tot), 1e-10f);
    float scn = SCRT * n;
    float f = tanhf(scn) / scn;
    yy[j] = f * f * tot;
    fj[j] = f;
  }
}

// ---------------------------------------------------------------------------
// Kernel 5: query stats from qt bf16: xx = f^2*sumsq; fi = f.
__global__ void k_qstat(const unsigned short* __restrict__ qt,
                        float* __restrict__ xx, float* __restrict__ fi) {
  int i = blockIdx.x;
  int t = threadIdx.x;
  ushort4 v = ((const ushort4*)(qt + (size_t)i * 1024))[t];
  float a = bf2f(v.x), b = bf2f(v.y), c = bf2f(v.z), d = bf2f(v.w);
  float ss = a * a + b * b + c * c + d * d;
#pragma unroll
  for (int off = 32; off > 0; off >>= 1) ss += __shfl_down(ss, off, 64);
  __shared__ float red[4];
  if ((t & 63) == 0) red[t >> 6] = ss;
  __syncthreads();
  if (t == 0) {
    float tot = red[0] + red[1] + red[2] + red[3];
    float n = fmaxf(sqrtf(tot), 1e-10f);
    float scn = SCRT * n;
    float f = tanhf(scn) / scn;
    xx[i] = f * f * tot;
    fi[i] = f;
  }
}

// ---------------------------------------------------------------------------
// 256x256-tile GEMM, 8 waves (2M x 4N), BK=32, 4 LDS slots (3 tiles ahead),
// m201-style phase discipline: per phase {ds_read frags || stage -> s_barrier
// -> lgkmcnt(0) -> sched_barrier -> setprio(1) 16xMFMA setprio(0) -> s_barrier}
// vmcnt gated once per K-tile (steady vmcnt(8), tail 4 -> 0).
template<int K, bool G2>
__global__ __launch_bounds__(512, 2) void k_gemm256(
    const unsigned short* __restrict__ A,
    const unsigned short* __restrict__ BT,
    unsigned short* __restrict__ Cq,
    const float* __restrict__ xx, const float* __restrict__ fi,
    const float* __restrict__ yy, const float* __restrict__ fj,
    const float* __restrict__ bias, float* __restrict__ out,
    int nxb) {
  constexpr int NT = K / 32;
  // 4 slots x (256 rows x 32 k) bf16 = 4 x 16 KB each for A and B = 128 KB
  __shared__ __align__(16) unsigned short AS[4 * 8192];
  __shared__ __align__(16) unsigned short BS[4 * 8192];

  // XCD-aware swizzle (grid divisible by 8)
  int nwg = gridDim.x;
  int bid = blockIdx.x;
  int wg = (bid & 7) * (nwg >> 3) + (bid >> 3);
  int bx = wg % nxb;
  int by = wg / nxb;
  size_t gm0 = (size_t)by * 256;
  int gn0 = bx * 256;

  int t = threadIdx.x;
  int lane = t & 63;
  int w = t >> 6;        // 0..7
  int wm = w >> 2;       // 0..1 -> 128-row block
  int wn = w & 3;        // 0..3 -> 64-col block
  int fr = lane & 15;
  int k0 = lane >> 4;

  // staging source (pre-swizzled global column so LDS ends up XOR-swizzled)
  int srow = t >> 2;                       // 0..127
  int ch = (t & 3) ^ ((srow >> 1) & 3);
  const unsigned short* pa0 = A + (gm0 + srow) * (size_t)K + ch * 8;
  const unsigned short* pa1 = pa0 + (size_t)128 * K;
  int br0 = gn0 + srow, br1 = gn0 + 128 + srow;
  if (G2) { br0 = min(br0, 1999); br1 = min(br1, 1999); }
  const unsigned short* pb0 = BT + (size_t)br0 * K + ch * 8;
  const unsigned short* pb1 = BT + (size_t)br1 * K + ch * 8;

  char* aw = (char*)AS + w * 1024;         // wave-uniform LDS stage base
  char* bw = (char*)BS + w * 1024;

  // fragment read base: (row>>1)&3 depends only on fr for all our row offsets
  unsigned fca = (unsigned)((k0 ^ ((fr >> 1) & 3)) << 4);
  const char* ard = (const char*)AS + (wm * 128 + fr) * 64 + fca;
  const char* brd = (const char*)BS + (wn * 64 + fr) * 64 + fca;

  f32x4 acc[8][4] = {};

  // prologue: stage tiles 0,1,2 into slots 0,1,2 (12 loads/thread)
#pragma unroll
  for (int p = 0; p < 3; ++p) {
    int ko = p * 32;
    GLOAD16(pa0 + ko, aw + p * 16384);
    GLOAD16(pa1 + ko, aw + p * 16384 + 8192);
    GLOAD16(pb0 + ko, bw + p * 16384);
    GLOAD16(pb1 + ko, bw + p * 16384 + 8192);
  }
  asm volatile("s_waitcnt vmcnt(8)" ::: "memory");  // tile 0 landed
  __builtin_amdgcn_s_barrier();
  asm volatile("" ::: "memory");

  for (int kt = 0; kt < NT; ++kt) {
    int cur = kt & 3;
    int stg = (kt + 3) & 3;
    const char* ac = ard + cur * 16384;
    const char* bc = brd + cur * 16384;
    bool do_stage = (kt + 3 < NT);
    int ko = (kt + 3) * 32;

    // ================= Phase 0: frags a0(m0-3) + b(n0-3); stage next A ======
    short8 a0[4], bv[4], a1[4];
#pragma unroll
    for (int m = 0; m < 4; ++m) a0[m] = *(const short8*)(ac + m * 1024);
#pragma unroll
    for (int n = 0; n < 4; ++n) bv[n] = *(const short8*)(bc + n * 1024);
    if (do_stage) {
      GLOAD16(pa0 + ko, aw + stg * 16384);
      GLOAD16(pa1 + ko, aw + stg * 16384 + 8192);
    }
    asm volatile("" ::: "memory");          // pin reads above the barrier
    __builtin_amdgcn_s_barrier();
    asm volatile("s_waitcnt lgkmcnt(0)" ::: "memory");
    __builtin_amdgcn_sched_barrier(0);
    __builtin_amdgcn_s_setprio(1);
#pragma unroll
    for (int m = 0; m < 4; ++m)
#pragma unroll
      for (int n = 0; n < 4; ++n)
        acc[m][n] = __builtin_amdgcn_mfma_f32_16x16x32_bf16(a0[m], bv[n], acc[m][n], 0, 0, 0);
    __builtin_amdgcn_s_setprio(0);
    __builtin_amdgcn_s_barrier();
    asm volatile("" ::: "memory");

    // ================= Phase 1: frags a1(m4-7); stage next B; vmcnt gate ====
#pragma unroll
    for (int m = 0; m < 4; ++m) a1[m] = *(const short8*)(ac + 4096 + m * 1024);
    if (do_stage) {
      GLOAD16(pb0 + ko, bw + stg * 16384);
      GLOAD16(pb1 + ko, bw + stg * 16384 + 8192);
    }
    // gate tile kt+1 (FIFO: 12 outstanding in steady state, drain oldest 4)
    if (kt < NT - 3) {
      asm volatile("s_waitcnt vmcnt(8)" ::: "memory");
    } else if (kt == NT - 3) {
      asm volatile("s_waitcnt vmcnt(4)" ::: "memory");
    } else if (kt == NT - 2) {
      asm volatile("s_waitcnt vmcnt(0)" ::: "memory");
    }
    __builtin_amdgcn_s_barrier();
    asm volatile("s_waitcnt lgkmcnt(0)" ::: "memory");
    __builtin_amdgcn_sched_barrier(0);
    __builtin_amdgcn_s_setprio(1);
#pragma unroll
    for (int m = 0; m < 4; ++m)
#pragma unroll
      for (int n = 0; n < 4; ++n)
        acc[4 + m][n] = __builtin_amdgcn_mfma_f32_16x16x32_bf16(a1[m], bv[n], acc[4 + m][n], 0, 0, 0);
    __builtin_amdgcn_s_setprio(0);
    if (kt < NT - 1) {
      __builtin_amdgcn_s_barrier();
      asm volatile("" ::: "memory");
    }
  }

  // ---- epilogue
  if (!G2) {
#pragma unroll
    for (int m = 0; m < 8; ++m)
#pragma unroll
      for (int n = 0; n < 4; ++n) {
        int col = gn0 + wn * 64 + n * 16 + fr;
        size_t row0 = gm0 + wm * 128 + m * 16 + k0 * 4;
#pragma unroll
        for (int j = 0; j < 4; ++j)
          Cq[(row0 + j) * 1024 + col] = f2bf(acc[m][n][j]);
      }
  } else {
#pragma unroll
    for (int m = 0; m < 8; ++m)
#pragma unroll
      for (int n = 0; n < 4; ++n) {
        int col = gn0 + wn * 64 + n * 16 + fr;
        if (col < 2000) {
          float yj = yy[col], fjc = fj[col], bj = bias[col];
          size_t row0 = gm0 + wm * 128 + m * 16 + k0 * 4;
#pragma unroll
          for (int j = 0; j < 4; ++j) {
            size_t row = row0 + j;
            float G = acc[m][n][j];
            float xi = xx[row], fic = fi[row];
            float xyv = -(fic * fjc) * G;
            float Aa = 1.0f + 2.0f * CC * xyv + CC * yj;
            float Bb = 1.0f - CC * xi;
            float num = Aa * Aa * xi + 2.0f * Aa * Bb * xyv + Bb * Bb * yj;
            float den = 1.0f + 2.0f * CC * xyv + CC * CC * xi * yj;
            out[row * 2000 + col] = -(num / (den * den)) + bj;
          }
        }
      }
  }
}

// ---------------------------------------------------------------------------
extern "C" void kernel_launch(void* const* d_in, const int* in_sizes, int n_in,
                              void* d_out, int out_size, void* d_ws, size_t ws_size,
                              hipStream_t stream) {
  const float* ent = (const float*)d_in[0];
  const float* rel = (const float*)d_in[1];
  const int* trip = (const int*)d_in[2];
  const float* Ws = (const float*)d_in[3];
  const float* Wo = (const float*)d_in[4];
  const float* bias = (const float*)d_in[5];
  float* out = (float*)d_out;

  char* ws = (char*)d_ws;
  unsigned short* sto = (unsigned short*)(ws);                    // 32768*2048*2 = 134217728
  unsigned short* wt  = (unsigned short*)(ws + 134217728);        // 1024*2048*2  =   4194304
  unsigned short* qt  = (unsigned short*)(ws + 138412032);        // 32768*1024*2 =  67108864
  unsigned short* relb= (unsigned short*)(ws + 205520896);        // 2000*1024*2  =   4096000
  float* xx = (float*)(ws + 209616896);                           // 131072
  float* fi = (float*)(ws + 209747968);                           // 131072
  float* yy = (float*)(ws + 209879040);                           // 8192
  float* fj = (float*)(ws + 209887232);                           // 8192

  k_prep_sto<<<dim3(32768), dim3(256), 0, stream>>>(ent, trip, sto);
  k_wt<<<dim3((1024 * 2048) / 256), dim3(256), 0, stream>>>(Ws, Wo, wt);
  k_rel<<<dim3(2000), dim3(256), 0, stream>>>(rel, relb, yy, fj);

  // GEMM1: qt[32768][1024] = sto[32768][2048] @ wt^T ; grid 4x128 = 512
  k_gemm256<2048, false><<<dim3(512), dim3(512), 0, stream>>>(
      sto, wt, qt, xx, fi, yy, fj, bias, out, 4);

  k_qstat<<<dim3(32768), dim3(256), 0, stream>>>(qt, xx, fi);

  // GEMM2 + epilogue: grid 8x128 = 1024
  k_gemm256<1024, true><<<dim3(1024), dim3(512), 0, stream>>>(
      qt, relb, qt /*unused*/, xx, fi, yy, fj, bias, out, 8);
}

// Round 4
// 435.806 us; speedup vs baseline: 1.1214x; 1.0097x over previous
//
#include <hip/hip_runtime.h>
#include <hip/hip_bf16.h>

typedef __attribute__((ext_vector_type(8))) short short8;
typedef __attribute__((ext_vector_type(4))) float f32x4;

#define CC 0.01f
#define SCRT 0.1f  // sqrt(c)

static __device__ __forceinline__ unsigned short f2bf(float f) {
  union { float f; unsigned int u; } cv; cv.f = f;
  unsigned int u = cv.u;
  unsigned int r = (u + 0x7fffu + ((u >> 16) & 1u)) >> 16;  // RNE
  return (unsigned short)r;
}
static __device__ __forceinline__ float bf2f(unsigned short u) {
  union { unsigned int u; float f; } cv; cv.u = ((unsigned int)u) << 16;
  return cv.f;
}

#define GLOAD16(g, l) __builtin_amdgcn_global_load_lds( \
    (const __attribute__((address_space(1))) void*)(g), \
    (__attribute__((address_space(3))) void*)(l), 16, 0, 0)

// ---------------------------------------------------------------------------
// Kernel 1: gather entity rows for s,o; apply log-map scale; write bf16.
__global__ void k_prep_sto(const float* __restrict__ ent,
                           const int* __restrict__ trip,
                           unsigned short* __restrict__ sto) {
  int i = blockIdx.x;
  int t = threadIdx.x;
  size_t si = (size_t)trip[i * 3 + 0];
  size_t oi = (size_t)trip[i * 3 + 2];
  float4 vs = ((const float4*)(ent + si * 1024))[t];
  float4 vo = ((const float4*)(ent + oi * 1024))[t];
  float ss = vs.x * vs.x + vs.y * vs.y + vs.z * vs.z + vs.w * vs.w;
  float so = vo.x * vo.x + vo.y * vo.y + vo.z * vo.z + vo.w * vo.w;
#pragma unroll
  for (int off = 32; off > 0; off >>= 1) {
    ss += __shfl_down(ss, off, 64);
    so += __shfl_down(so, off, 64);
  }
  __shared__ float red[8];
  if ((t & 63) == 0) { red[t >> 6] = ss; red[4 + (t >> 6)] = so; }
  __syncthreads();
  float tot_s = red[0] + red[1] + red[2] + red[3];
  float tot_o = red[4] + red[5] + red[6] + red[7];

  float ns = fmaxf(sqrtf(tot_s), 1e-10f);
  float scn_s = SCRT * ns;
  float fs = atanhf(fminf(scn_s, 1.0f - 1e-7f)) / scn_s;

  float no = fmaxf(sqrtf(tot_o), 1e-10f);
  float scn_o = SCRT * no;
  float fo = atanhf(fminf(scn_o, 1.0f - 1e-7f)) / scn_o;

  ushort4 os, oo;
  os.x = f2bf(vs.x * fs); os.y = f2bf(vs.y * fs);
  os.z = f2bf(vs.z * fs); os.w = f2bf(vs.w * fs);
  oo.x = f2bf(vo.x * fo); oo.y = f2bf(vo.y * fo);
  oo.z = f2bf(vo.z * fo); oo.w = f2bf(vo.w * fo);
  ((ushort4*)(sto + (size_t)i * 2048))[t] = os;
  ((ushort4*)(sto + (size_t)i * 2048 + 1024))[t] = oo;
}

// ---------------------------------------------------------------------------
// Kernel 2: build wt[n][k] = (k<1024 ? W_s[k][n] : W_o[k-1024][n]) as bf16.
__global__ void k_wt(const float* __restrict__ Ws, const float* __restrict__ Wo,
                     unsigned short* __restrict__ wtb) {
  int idx = blockIdx.x * 256 + threadIdx.x;   // 1024*2048 total
  int n = idx >> 11;
  int k = idx & 2047;
  float v = (k < 1024) ? Ws[k * 1024 + n] : Wo[(k - 1024) * 1024 + n];
  wtb[idx] = f2bf(v);
}

// ---------------------------------------------------------------------------
// Kernel 3: rel prep: relb = bf16(rel_embedding); yy = f^2*sumsq; fj = f.
__global__ void k_rel(const float* __restrict__ rel,
                      unsigned short* __restrict__ relb,
                      float* __restrict__ yy, float* __restrict__ fj) {
  int j = blockIdx.x;
  int t = threadIdx.x;
  float4 v = ((const float4*)(rel + (size_t)j * 1024))[t];
  float ss = v.x * v.x + v.y * v.y + v.z * v.z + v.w * v.w;
#pragma unroll
  for (int off = 32; off > 0; off >>= 1) ss += __shfl_down(ss, off, 64);
  __shared__ float red[4];
  if ((t & 63) == 0) red[t >> 6] = ss;
  __syncthreads();
  ushort4 o;
  o.x = f2bf(v.x); o.y = f2bf(v.y); o.z = f2bf(v.z); o.w = f2bf(v.w);
  ((ushort4*)(relb + (size_t)j * 1024))[t] = o;
  if (t == 0) {
    float tot = red[0] + red[1] + red[2] + red[3];
    float n = fmaxf(sqrtf(tot), 1e-10f);
    float scn = SCRT * n;
    float f = tanhf(scn) / scn;
    yy[j] = f * f * tot;
    fj[j] = f;
  }
}

// ---------------------------------------------------------------------------
// Kernel 5: query stats from qt bf16: xx = f^2*sumsq; fi = f.
__global__ void k_qstat(const unsigned short* __restrict__ qt,
                        float* __restrict__ xx, float* __restrict__ fi) {
  int i = blockIdx.x;
  int t = threadIdx.x;
  ushort4 v = ((const ushort4*)(qt + (size_t)i * 1024))[t];
  float a = bf2f(v.x), b = bf2f(v.y), c = bf2f(v.z), d = bf2f(v.w);
  float ss = a * a + b * b + c * c + d * d;
#pragma unroll
  for (int off = 32; off > 0; off >>= 1) ss += __shfl_down(ss, off, 64);
  __shared__ float red[4];
  if ((t & 63) == 0) red[t >> 6] = ss;
  __syncthreads();
  if (t == 0) {
    float tot = red[0] + red[1] + red[2] + red[3];
    float n = fmaxf(sqrtf(tot), 1e-10f);
    float scn = SCRT * n;
    float f = tanhf(scn) / scn;
    xx[i] = f * f * tot;
    fi[i] = f;
  }
}

// ---------------------------------------------------------------------------
// 256x256-tile GEMM, 8 waves (2M x 4N), BK=32, 4 LDS slots (3 tiles ahead).
// Register read-ahead schedule: ds_reads issue UNDER the MFMA cluster and are
// retired by counted lgkmcnt; one s_barrier per K-tile; counted vmcnt FIFO.
template<int K, bool G2>
__global__ __launch_bounds__(512, 2) void k_gemm256(
    const unsigned short* __restrict__ A,
    const unsigned short* __restrict__ BT,
    unsigned short* __restrict__ Cq,
    const float* __restrict__ xx, const float* __restrict__ fi,
    const float* __restrict__ yy, const float* __restrict__ fj,
    const float* __restrict__ bias, float* __restrict__ out,
    int nxb) {
  constexpr int NT = K / 32;
  // 4 slots x (256 rows x 32 k) bf16 = 4 x 16 KB each for A and B = 128 KB
  __shared__ __align__(16) unsigned short AS[4 * 8192];
  __shared__ __align__(16) unsigned short BS[4 * 8192];

  // XCD-aware swizzle (grid divisible by 8)
  int nwg = gridDim.x;
  int bid = blockIdx.x;
  int wg = (bid & 7) * (nwg >> 3) + (bid >> 3);
  int bx = wg % nxb;
  int by = wg / nxb;
  size_t gm0 = (size_t)by * 256;
  int gn0 = bx * 256;

  int t = threadIdx.x;
  int lane = t & 63;
  int w = t >> 6;        // 0..7
  int wm = w >> 2;       // 0..1 -> 128-row block
  int wn = w & 3;        // 0..3 -> 64-col block
  int fr = lane & 15;
  int k0 = lane >> 4;

  // staging source (pre-swizzled global column so LDS ends up XOR-swizzled)
  int srow = t >> 2;                       // 0..127
  int ch = (t & 3) ^ ((srow >> 1) & 3);
  const unsigned short* pa0 = A + (gm0 + srow) * (size_t)K + ch * 8;
  const unsigned short* pa1 = pa0 + (size_t)128 * K;
  int br0 = gn0 + srow, br1 = gn0 + 128 + srow;
  if (G2) { br0 = min(br0, 1999); br1 = min(br1, 1999); }
  const unsigned short* pb0 = BT + (size_t)br0 * K + ch * 8;
  const unsigned short* pb1 = BT + (size_t)br1 * K + ch * 8;

  char* aw = (char*)AS + w * 1024;         // wave-uniform LDS stage base
  char* bw = (char*)BS + w * 1024;

  // fragment read base: (row>>1)&3 depends only on fr for all our row offsets
  unsigned fca = (unsigned)((k0 ^ ((fr >> 1) & 3)) << 4);
  const char* ard = (const char*)AS + (wm * 128 + fr) * 64 + fca;
  const char* brd = (const char*)BS + (wn * 64 + fr) * 64 + fca;

  f32x4 acc[8][4] = {};
  short8 aA[4], bA[4], aB[4], bB[4], a1[4];

  // prologue: stage tiles 0,1,2 into slots 0,1,2 (12 loads/thread)
#pragma unroll
  for (int p = 0; p < 3; ++p) {
    int ko = p * 32;
    GLOAD16(pa0 + ko, aw + p * 16384);
    GLOAD16(pa1 + ko, aw + p * 16384 + 8192);
    GLOAD16(pb0 + ko, bw + p * 16384);
    GLOAD16(pb1 + ko, bw + p * 16384 + 8192);
  }
  asm volatile("s_waitcnt vmcnt(8)" ::: "memory");   // tile 0 landed
  asm volatile("s_waitcnt lgkmcnt(0)" ::: "memory"); // drain SMEM (kernargs)
  __builtin_amdgcn_s_barrier();
  __builtin_amdgcn_sched_barrier(0);
  // prologue reads for kt=0 phase 0 (retired at kt=0's lgkmcnt(4))
#pragma unroll
  for (int m = 0; m < 4; ++m) aA[m] = *(const short8*)(ard + m * 1024);
#pragma unroll
  for (int n = 0; n < 4; ++n) bA[n] = *(const short8*)(brd + n * 1024);

  // One K-tile body. ca/cb: current frag regs. na/nb: next-tile frag regs.
  auto body = [&](int kt, short8 (&ca)[4], short8 (&cb)[4],
                  short8 (&na)[4], short8 (&nb)[4]) __attribute__((always_inline)) {
    int cur = kt & 3;
    int stg = (kt + 3) & 3;
    const char* ac = ard + cur * 16384;
    bool st = kt + 3 < NT;
    int ko = (kt + 3) * 32;

    // ---- phase 0: issue a1 reads (overlap with MFMA below); stage A
#pragma unroll
    for (int m = 0; m < 4; ++m) a1[m] = *(const short8*)(ac + 4096 + m * 1024);
    if (st) {
      GLOAD16(pa0 + ko, aw + stg * 16384);
      GLOAD16(pa1 + ko, aw + stg * 16384 + 8192);
    }
    // retire prev phase-1's 8 reads (ca/cb); leave the 4 a1 reads in flight
    asm volatile("s_waitcnt lgkmcnt(4)" ::: "memory");
    __builtin_amdgcn_sched_barrier(0);
    __builtin_amdgcn_s_setprio(1);
#pragma unroll
    for (int m = 0; m < 4; ++m)
#pragma unroll
      for (int n = 0; n < 4; ++n)
        acc[m][n] = __builtin_amdgcn_mfma_f32_16x16x32_bf16(ca[m], cb[n], acc[m][n], 0, 0, 0);
    __builtin_amdgcn_s_setprio(0);

    // stage B; retire a1 (all reads of slot cur now sampled); gate tile kt+1
    if (st) {
      GLOAD16(pb0 + ko, bw + stg * 16384);
      GLOAD16(pb1 + ko, bw + stg * 16384 + 8192);
    }
    asm volatile("s_waitcnt lgkmcnt(0)" ::: "memory");
    if (kt < NT - 3) {
      asm volatile("s_waitcnt vmcnt(8)" ::: "memory");
    } else if (kt == NT - 3) {
      asm volatile("s_waitcnt vmcnt(4)" ::: "memory");
    } else if (kt == NT - 2) {
      asm volatile("s_waitcnt vmcnt(0)" ::: "memory");
    }
    if (kt < NT - 1) __builtin_amdgcn_s_barrier();
    __builtin_amdgcn_sched_barrier(0);

    // ---- phase 1: issue next-tile reads (overlap with MFMA below)
    if (kt < NT - 1) {
      int nxt = (kt + 1) & 3;
      const char* an = ard + nxt * 16384;
      const char* bn = brd + nxt * 16384;
#pragma unroll
      for (int m = 0; m < 4; ++m) na[m] = *(const short8*)(an + m * 1024);
#pragma unroll
      for (int n = 0; n < 4; ++n) nb[n] = *(const short8*)(bn + n * 1024);
    }
    __builtin_amdgcn_s_setprio(1);
#pragma unroll
    for (int m = 0; m < 4; ++m)
#pragma unroll
      for (int n = 0; n < 4; ++n)
        acc[4 + m][n] = __builtin_amdgcn_mfma_f32_16x16x32_bf16(a1[m], cb[n], acc[4 + m][n], 0, 0, 0);
    __builtin_amdgcn_s_setprio(0);
  };

  for (int kt = 0; kt < NT; kt += 2) {
    body(kt, aA, bA, aB, bB);
    body(kt + 1, aB, bB, aA, bA);
  }
  asm volatile("s_waitcnt lgkmcnt(0)" ::: "memory");

  // ---- epilogue
  if (!G2) {
#pragma unroll
    for (int m = 0; m < 8; ++m)
#pragma unroll
      for (int n = 0; n < 4; ++n) {
        int col = gn0 + wn * 64 + n * 16 + fr;
        size_t row0 = gm0 + wm * 128 + m * 16 + k0 * 4;
#pragma unroll
        for (int j = 0; j < 4; ++j)
          Cq[(row0 + j) * 1024 + col] = f2bf(acc[m][n][j]);
      }
  } else {
#pragma unroll
    for (int m = 0; m < 8; ++m)
#pragma unroll
      for (int n = 0; n < 4; ++n) {
        int col = gn0 + wn * 64 + n * 16 + fr;
        if (col < 2000) {
          float yj = yy[col], fjc = fj[col], bj = bias[col];
          size_t row0 = gm0 + wm * 128 + m * 16 + k0 * 4;
#pragma unroll
          for (int j = 0; j < 4; ++j) {
            size_t row = row0 + j;
            float G = acc[m][n][j];
            float xi = xx[row], fic = fi[row];
            float xyv = -(fic * fjc) * G;
            float Aa = 1.0f + 2.0f * CC * xyv + CC * yj;
            float Bb = 1.0f - CC * xi;
            float num = Aa * Aa * xi + 2.0f * Aa * Bb * xyv + Bb * Bb * yj;
            float den = 1.0f + 2.0f * CC * xyv + CC * CC * xi * yj;
            out[row * 2000 + col] = -(num / (den * den)) + bj;
          }
        }
      }
  }
}

// ---------------------------------------------------------------------------
extern "C" void kernel_launch(void* const* d_in, const int* in_sizes, int n_in,
                              void* d_out, int out_size, void* d_ws, size_t ws_size,
                              hipStream_t stream) {
  const float* ent = (const float*)d_in[0];
  const float* rel = (const float*)d_in[1];
  const int* trip = (const int*)d_in[2];
  const float* Ws = (const float*)d_in[3];
  const float* Wo = (const float*)d_in[4];
  const float* bias = (const float*)d_in[5];
  float* out = (float*)d_out;

  char* ws = (char*)d_ws;
  unsigned short* sto = (unsigned short*)(ws);                    // 32768*2048*2 = 134217728
  unsigned short* wt  = (unsigned short*)(ws + 134217728);        // 1024*2048*2  =   4194304
  unsigned short* qt  = (unsigned short*)(ws + 138412032);        // 32768*1024*2 =  67108864
  unsigned short* relb= (unsigned short*)(ws + 205520896);        // 2000*1024*2  =   4096000
  float* xx = (float*)(ws + 209616896);                           // 131072
  float* fi = (float*)(ws + 209747968);                           // 131072
  float* yy = (float*)(ws + 209879040);                           // 8192
  float* fj = (float*)(ws + 209887232);                           // 8192

  k_prep_sto<<<dim3(32768), dim3(256), 0, stream>>>(ent, trip, sto);
  k_wt<<<dim3((1024 * 2048) / 256), dim3(256), 0, stream>>>(Ws, Wo, wt);
  k_rel<<<dim3(2000), dim3(256), 0, stream>>>(rel, relb, yy, fj);

  // GEMM1: qt[32768][1024] = sto[32768][2048] @ wt^T ; grid 4x128 = 512
  k_gemm256<2048, false><<<dim3(512), dim3(512), 0, stream>>>(
      sto, wt, qt, xx, fi, yy, fj, bias, out, 4);

  k_qstat<<<dim3(32768), dim3(256), 0, stream>>>(qt, xx, fi);

  // GEMM2 + epilogue: grid 8x128 = 1024
  k_gemm256<1024, true><<<dim3(1024), dim3(512), 0, stream>>>(
      qt, relb, qt /*unused*/, xx, fi, yy, fj, bias, out, 8);
}